// Round 9
// baseline (363.059 us; speedup 1.0000x reference)
//
#include <hip/hip_runtime.h>
#include <hip/hip_bf16.h>
#include <stdint.h>

// GPTQOFTLinear: y = (x @ R_blockdiag) @ W^T + b
// W' = W with each 64-col block right-multiplied by Q_r^T; y = x @ W'^T + b.
// cayley (Neumann, reg-vector) -> fold W' via MFMA -> cast x bf16 -> 256^2 8-phase GEMM.
// r9: GEMM fragments switched 16x16x32 -> 32x32x16 (m119: 2495 vs 2176 TF ceiling, -17%
// matrix-pipe time, half the issue slots). Schedule/ledger/swizzle frozen from r8.

typedef __bf16 bf16;
typedef __attribute__((ext_vector_type(4))) __bf16 bf16x4;
typedef __attribute__((ext_vector_type(8))) __bf16 bf16x8;
typedef __attribute__((ext_vector_type(4))) float f32x4;
typedef __attribute__((ext_vector_type(16))) float f32x16;

__device__ __forceinline__ bf16 f2bf(float f) {
  unsigned u = __builtin_bit_cast(unsigned, f);
  u += 0x7fffu + ((u >> 16) & 1u);          // RNE
  unsigned short h = (unsigned short)(u >> 16);
  return __builtin_bit_cast(bf16, h);
}

// ---------------- Kernel 1: Cayley via Neumann series (St-transposed, vec broadcasts) ----
__global__ __launch_bounds__(256) void cayley_kernel(const float* __restrict__ oft_r,
                                                     float* __restrict__ Qxt) {
  __shared__ float St[64][68];
  __shared__ float Ta[64][65];
  __shared__ float Tb[64][65];
  const int tid = threadIdx.x;
  const int r = blockIdx.x;
  const float* D = oft_r + (size_t)r * 4096;

  for (int idx = tid; idx < 4096; idx += 256) {
    int i = idx >> 6, j = idx & 63;
    float s = 0.5f * (D[i * 64 + j] - D[j * 64 + i]);
    St[j][i] = s;
    Ta[i][j] = (i == j ? 1.0f : 0.0f) - s;   // T0 = I - S
  }
  __syncthreads();

  const int j = tid & 63;
  const int w = tid >> 6;
  float (*Tin)[65] = Ta;
  float (*Tout)[65] = Tb;

  for (int it = 0; it < 5; ++it) {           // final T = order-6 series
    float out[16];
#pragma unroll
    for (int m = 0; m < 16; ++m) out[m] = ((w * 16 + m) == j ? 1.0f : 0.0f);
    for (int c = 0; c < 64; ++c) {
      float tc = Tin[c][j];
      f32x4 s0 = *reinterpret_cast<const f32x4*>(&St[c][w * 16]);
      f32x4 s1 = *reinterpret_cast<const f32x4*>(&St[c][w * 16 + 4]);
      f32x4 s2 = *reinterpret_cast<const f32x4*>(&St[c][w * 16 + 8]);
      f32x4 s3 = *reinterpret_cast<const f32x4*>(&St[c][w * 16 + 12]);
#pragma unroll
      for (int q = 0; q < 4; ++q) {
        out[q]      -= s0[q] * tc;
        out[4 + q]  -= s1[q] * tc;
        out[8 + q]  -= s2[q] * tc;
        out[12 + q] -= s3[q] * tc;
      }
    }
#pragma unroll
    for (int m = 0; m < 16; ++m) Tout[w * 16 + m][j] = out[m];
    __syncthreads();
    float (*tmp)[65] = Tin; Tin = Tout; Tout = tmp;
  }
  {
    float out[16];
#pragma unroll
    for (int m = 0; m < 16; ++m) out[m] = Tin[w * 16 + m][j];
    for (int c = 0; c < 64; ++c) {
      float tc = Tin[c][j];
      f32x4 s0 = *reinterpret_cast<const f32x4*>(&St[c][w * 16]);
      f32x4 s1 = *reinterpret_cast<const f32x4*>(&St[c][w * 16 + 4]);
      f32x4 s2 = *reinterpret_cast<const f32x4*>(&St[c][w * 16 + 8]);
      f32x4 s3 = *reinterpret_cast<const f32x4*>(&St[c][w * 16 + 12]);
#pragma unroll
      for (int q = 0; q < 4; ++q) {
        out[q]      -= s0[q] * tc;
        out[4 + q]  -= s1[q] * tc;
        out[8 + q]  -= s2[q] * tc;
        out[12 + q] -= s3[q] * tc;
      }
    }
#pragma unroll
    for (int m = 0; m < 16; ++m) Qxt[(size_t)r * 4096 + (w * 16 + m) * 64 + j] = out[m];
  }
}

// ---------------- Kernel 2: fold rotation into W via MFMA ----------------
__global__ __launch_bounds__(256) void fold_w_kernel(const float* __restrict__ W,
                                                     const float* __restrict__ Qxt,
                                                     bf16* __restrict__ Wp) {
  __shared__ bf16 Wb[128 * 64];
  __shared__ bf16 Xt[64 * 64];
  const int tid = threadIdx.x;
  const int lane = tid & 63;
  const int wave = tid >> 6;
  const int o0 = blockIdx.x * 128;
  const int r = blockIdx.y;
  const int fr = lane & 15;
  const int kg = lane >> 4;

#pragma unroll
  for (int i = 0; i < 8; ++i) {
    int c = i * 256 + tid;
    int row = c >> 4, c4 = c & 15;
    f32x4 v = *reinterpret_cast<const f32x4*>(W + (size_t)(o0 + row) * 4096 + r * 64 + c4 * 4);
    bf16x4 o; o[0] = f2bf(v[0]); o[1] = f2bf(v[1]); o[2] = f2bf(v[2]); o[3] = f2bf(v[3]);
    *reinterpret_cast<bf16x4*>(&Wb[row * 64 + c4 * 4]) = o;
  }
#pragma unroll
  for (int i = 0; i < 4; ++i) {
    int c = i * 256 + tid;
    int row = c >> 4, c4 = c & 15;
    f32x4 v = *reinterpret_cast<const f32x4*>(Qxt + (size_t)r * 4096 + row * 64 + c4 * 4);
    bf16x4 o; o[0] = f2bf(v[0]); o[1] = f2bf(v[1]); o[2] = f2bf(v[2]); o[3] = f2bf(v[3]);
    *reinterpret_cast<bf16x4*>(&Xt[row * 64 + c4 * 4]) = o;
  }
  __syncthreads();

  const int wm = wave * 32;
  f32x4 acc[2][4];
#pragma unroll
  for (int mi = 0; mi < 2; ++mi)
#pragma unroll
    for (int ni = 0; ni < 4; ++ni) acc[mi][ni] = (f32x4){0.f, 0.f, 0.f, 0.f};

#pragma unroll
  for (int kk = 0; kk < 64; kk += 32) {
    bf16x8 af[2], bx[4];
#pragma unroll
    for (int mi = 0; mi < 2; ++mi)
      af[mi] = *reinterpret_cast<const bf16x8*>(&Wb[(wm + mi * 16 + fr) * 64 + kk + kg * 8]);
#pragma unroll
    for (int ni = 0; ni < 4; ++ni)
      bx[ni] = *reinterpret_cast<const bf16x8*>(&Xt[(ni * 16 + fr) * 64 + kk + kg * 8]);
#pragma unroll
    for (int mi = 0; mi < 2; ++mi)
#pragma unroll
      for (int ni = 0; ni < 4; ++ni)
        acc[mi][ni] = __builtin_amdgcn_mfma_f32_16x16x32_bf16(af[mi], bx[ni], acc[mi][ni], 0, 0, 0);
  }

#pragma unroll
  for (int mi = 0; mi < 2; ++mi)
#pragma unroll
    for (int ni = 0; ni < 4; ++ni)
#pragma unroll
      for (int q = 0; q < 4; ++q) {
        int row = o0 + wm + mi * 16 + kg * 4 + q;
        int col = ni * 16 + fr;
        Wp[(size_t)row * 4096 + r * 64 + col] = f2bf(acc[mi][ni][q]);
      }
}

// ---------------- Kernel 3: cast x to bf16 ----------------
__global__ __launch_bounds__(256) void cast_x_kernel(const float* __restrict__ x,
                                                     bf16* __restrict__ xb, long n) {
  long i0 = ((long)blockIdx.x * 256 + threadIdx.x) * 8;
  long stride = (long)gridDim.x * 256 * 8;
  for (long i = i0; i < n; i += stride) {
    f32x4 a = *reinterpret_cast<const f32x4*>(x + i);
    f32x4 b = *reinterpret_cast<const f32x4*>(x + i + 4);
    bf16x8 o;
    o[0] = f2bf(a[0]); o[1] = f2bf(a[1]); o[2] = f2bf(a[2]); o[3] = f2bf(a[3]);
    o[4] = f2bf(b[0]); o[5] = f2bf(b[1]); o[6] = f2bf(b[2]); o[7] = f2bf(b[3]);
    *reinterpret_cast<bf16x8*>(xb + i) = o;
  }
}

// ---------------- Kernel 4: 256x256 8-phase GEMM (32x32x16 frags) ----------------
// A [M,K] bf16 row-major, B [N,K] bf16 row-major (B^T layout), C [M,N] f32.
// 512 thr = 8 waves (2M x 4N); per-wave 128x64 = 4 mb(32) x 2 nb(32). BK=64 in two
// K-halves; double-buffered 128 KiB LDS; swizzle key (row>>1)&3 (2-way free for the
// 32-row frag reads too — same quarter-wave structure). Ledger frozen from r4/r5.
// A-frag (32x32x16): lane holds row=lane&31, k=(lane>>5)*8..+8 -> one b128.
// C/D: col=lane&31, row=(reg&3)+8*(reg>>2)+4*(lane>>5)  [m74/m101 verified].

#define GLDS16(g, l) __builtin_amdgcn_global_load_lds( \
    (const __attribute__((address_space(1))) unsigned int*)(g), \
    (__attribute__((address_space(3))) unsigned int*)(l), 16, 0, 0)

#define VMCNT4 asm volatile("s_waitcnt vmcnt(4)" ::: "memory")
#define VMCNT0 asm volatile("s_waitcnt vmcnt(0)" ::: "memory")
#define BARRIER() do { asm volatile("" ::: "memory"); \
  __builtin_amdgcn_s_barrier(); asm volatile("" ::: "memory"); } while (0)

#define MFMA32(AF, BF, ACC) ACC = __builtin_amdgcn_mfma_f32_32x32x16_bf16(AF, BF, ACC, 0, 0, 0)

// One K-tile = 4 phases. BUF literal; stage tile TN into BUF^1 when PRE.
#define DO_TILE(BUF, TN, PRE) do { \
    /* P0: ks0, mb0-1 */ \
    B0k0 = LDB32(BUF, 0, 0, 0); B0k1 = LDB32(BUF, 0, 0, 1); \
    B1k0 = LDB32(BUF, 0, 1, 0); B1k1 = LDB32(BUF, 0, 1, 1); \
    A0k0 = LDA32(BUF, 0, 0, 0); A0k1 = LDA32(BUF, 0, 0, 1); \
    A1k0 = LDA32(BUF, 0, 1, 0); A1k1 = LDA32(BUF, 0, 1, 1); \
    if (PRE) STAGE(TN, BUF ^ 1, 0); \
    BARRIER(); \
    __builtin_amdgcn_s_setprio(1); \
    MFMA32(A0k0, B0k0, acc00); MFMA32(A0k0, B1k0, acc01); \
    MFMA32(A1k0, B0k0, acc10); MFMA32(A1k0, B1k0, acc11); \
    MFMA32(A0k1, B0k1, acc00); MFMA32(A0k1, B1k1, acc01); \
    MFMA32(A1k1, B0k1, acc10); MFMA32(A1k1, B1k1, acc11); \
    __builtin_amdgcn_s_setprio(0); \
    BARRIER(); \
    /* P1: ks0, mb2-3 */ \
    A0k0 = LDA32(BUF, 0, 2, 0); A0k1 = LDA32(BUF, 0, 2, 1); \
    A1k0 = LDA32(BUF, 0, 3, 0); A1k1 = LDA32(BUF, 0, 3, 1); \
    if (PRE) STAGE(TN, BUF ^ 1, 1); \
    if (PRE) { VMCNT4; } else { VMCNT0; } \
    BARRIER(); \
    __builtin_amdgcn_s_setprio(1); \
    MFMA32(A0k0, B0k0, acc20); MFMA32(A0k0, B1k0, acc21); \
    MFMA32(A1k0, B0k0, acc30); MFMA32(A1k0, B1k0, acc31); \
    MFMA32(A0k1, B0k1, acc20); MFMA32(A0k1, B1k1, acc21); \
    MFMA32(A1k1, B0k1, acc30); MFMA32(A1k1, B1k1, acc31); \
    __builtin_amdgcn_s_setprio(0); \
    BARRIER(); \
    /* P2: ks1, mb0-1 */ \
    B0k0 = LDB32(BUF, 1, 0, 0); B0k1 = LDB32(BUF, 1, 0, 1); \
    B1k0 = LDB32(BUF, 1, 1, 0); B1k1 = LDB32(BUF, 1, 1, 1); \
    A0k0 = LDA32(BUF, 1, 0, 0); A0k1 = LDA32(BUF, 1, 0, 1); \
    A1k0 = LDA32(BUF, 1, 1, 0); A1k1 = LDA32(BUF, 1, 1, 1); \
    if (PRE) STAGE(TN, BUF ^ 1, 2); \
    BARRIER(); \
    __builtin_amdgcn_s_setprio(1); \
    MFMA32(A0k0, B0k0, acc00); MFMA32(A0k0, B1k0, acc01); \
    MFMA32(A1k0, B0k0, acc10); MFMA32(A1k0, B1k0, acc11); \
    MFMA32(A0k1, B0k1, acc00); MFMA32(A0k1, B1k1, acc01); \
    MFMA32(A1k1, B0k1, acc10); MFMA32(A1k1, B1k1, acc11); \
    __builtin_amdgcn_s_setprio(0); \
    BARRIER(); \
    /* P3: ks1, mb2-3 */ \
    A0k0 = LDA32(BUF, 1, 2, 0); A0k1 = LDA32(BUF, 1, 2, 1); \
    A1k0 = LDA32(BUF, 1, 3, 0); A1k1 = LDA32(BUF, 1, 3, 1); \
    if (PRE) STAGE(TN, BUF ^ 1, 3); \
    if (PRE) { VMCNT4; } else { VMCNT0; } \
    BARRIER(); \
    __builtin_amdgcn_s_setprio(1); \
    MFMA32(A0k0, B0k0, acc20); MFMA32(A0k0, B1k0, acc21); \
    MFMA32(A1k0, B0k0, acc30); MFMA32(A1k0, B1k0, acc31); \
    MFMA32(A0k1, B0k1, acc20); MFMA32(A0k1, B1k1, acc21); \
    MFMA32(A1k1, B0k1, acc30); MFMA32(A1k1, B1k1, acc31); \
    __builtin_amdgcn_s_setprio(0); \
    BARRIER(); \
  } while (0)

__global__ __launch_bounds__(512, 2) void gemm_kernel(const bf16* __restrict__ A,
                                                      const bf16* __restrict__ B,
                                                      const float* __restrict__ bias,
                                                      float* __restrict__ C,
                                                      int M, int N, int K) {
  __shared__ bf16 lds[65536];   // 128 KiB
  const int tid = threadIdx.x;
  const int lane = tid & 63;
  const int wave = tid >> 6;
  const int wr = wave >> 2;          // 0..1  (M)
  const int wc = wave & 3;           // 0..3  (N)
  const int l31 = lane & 31;
  const int lhi = lane >> 5;         // k-group within K=16 frag
  const int m0 = blockIdx.y * 256;
  const int n0 = blockIdx.x * 256;
  const int NT = K >> 6;             // 64, even

  f32x16 acc00 = {}, acc01 = {}, acc10 = {}, acc11 = {};
  f32x16 acc20 = {}, acc21 = {}, acc30 = {}, acc31 = {};

  // stage pair p (0:A-ks0 1:B-ks0 2:A-ks1 3:B-ks1) of K-tile t into LDS buffer db
  auto STAGE = [&](int t, int db, int p) {
    const int op = p & 1, ks = p >> 1;
    const bf16* src = op ? B : A;
    const int base_row = op ? n0 : m0;
    const int ldsb = db * 32768 + op * 16384 + ks * 8192;
#pragma unroll
    for (int i = 0; i < 2; ++i) {
      int c = i * 512 + tid;           // 1024 chunks of 16B per half-tile
      int row = c >> 2, cc = c & 3;
      const bf16* g = src + (size_t)(base_row + row) * K + t * 64 + ks * 32
                      + ((cc ^ ((row >> 1) & 3)) << 3);      // inverse-swizzled source
      GLDS16(g, &lds[ldsb + ((i * 512 + wave * 64) << 3)]); // linear dest (+lane*16B by HW)
    }
  };
  // 32x32x16 fragment loads: row = base + l31; chunk cc = ksub*2 + lhi (k = ksub*16 + lhi*8)
  auto LDA32 = [&](int buf, int ks, int mb, int ksub) -> bf16x8 {
    int row = wr * 128 + mb * 32 + l31;
    int cc = ksub * 2 + lhi;
    return *reinterpret_cast<const bf16x8*>(
        &lds[buf * 32768 + ks * 8192 + row * 32 + ((cc ^ ((row >> 1) & 3)) << 3)]);
  };
  auto LDB32 = [&](int buf, int ks, int nb, int ksub) -> bf16x8 {
    int row = wc * 64 + nb * 32 + l31;
    int cc = ksub * 2 + lhi;
    return *reinterpret_cast<const bf16x8*>(
        &lds[buf * 32768 + 16384 + ks * 8192 + row * 32 + ((cc ^ ((row >> 1) & 3)) << 3)]);
  };

  // prologue: stage tile 0 into buf0; publish its ks0 halves (ks1 pair stays in flight)
#pragma unroll
  for (int p = 0; p < 4; ++p) STAGE(0, 0, p);
  VMCNT4;
  BARRIER();

  bf16x8 A0k0, A0k1, A1k0, A1k1, B0k0, B0k1, B1k0, B1k1;
  for (int t = 0; t < NT; t += 2) {
    DO_TILE(0, t + 1, true);
    DO_TILE(1, t + 2, (t + 2) < NT);
  }

  // epilogue: 32x32 C/D layout: col = l31, row = (reg&3) + 8*(reg>>2) + 4*lhi
  const float bv0 = bias[n0 + wc * 64 + l31];
  const float bv1 = bias[n0 + wc * 64 + 32 + l31];
#define EPI(ACC, MB, NB, BV) \
  _Pragma("unroll") \
  for (int reg = 0; reg < 16; ++reg) { \
    int row = m0 + wr * 128 + MB * 32 + (reg & 3) + 8 * (reg >> 2) + 4 * lhi; \
    C[(size_t)row * N + (n0 + wc * 64 + NB * 32 + l31)] = ACC[reg] + BV; \
  }
  EPI(acc00, 0, 0, bv0) EPI(acc01, 0, 1, bv1)
  EPI(acc10, 1, 0, bv0) EPI(acc11, 1, 1, bv1)
  EPI(acc20, 2, 0, bv0) EPI(acc21, 2, 1, bv1)
  EPI(acc30, 3, 0, bv0) EPI(acc31, 3, 1, bv1)
#undef EPI
}

extern "C" void kernel_launch(void* const* d_in, const int* in_sizes, int n_in,
                              void* d_out, int out_size, void* d_ws, size_t ws_size,
                              hipStream_t stream) {
  const float* x     = (const float*)d_in[0];   // [2,4096,4096]
  const float* oft_r = (const float*)d_in[1];   // [64,64,64]
  const float* W     = (const float*)d_in[2];   // [4096,4096]
  const float* b     = (const float*)d_in[3];   // [4096]
  float* y = (float*)d_out;                     // [8192,4096] f32

  char* ws = (char*)d_ws;
  float* Qxt = (float*)ws;                                 // 1 MiB: Q row-major per block
  bf16*  Wp  = (bf16*)(ws + (1u << 20));                   // 32 MiB: folded W, bf16
  bf16*  xb  = (bf16*)(ws + (1u << 20) + (32u << 20));     // 64 MiB: x, bf16

  cayley_kernel<<<64, 256, 0, stream>>>(oft_r, Qxt);
  dim3 fg(32, 64);
  fold_w_kernel<<<fg, 256, 0, stream>>>(W, Qxt, Wp);
  cast_x_kernel<<<2048, 256, 0, stream>>>(x, xb, 33554432L);
  dim3 gg(4096 / 256, 8192 / 256);   // (16, 32)
  gemm_kernel<<<gg, 512, 0, stream>>>(xb, Wp, b, y, 8192, 4096, 4096);
}

// Round 10
// 316.260 us; speedup vs baseline: 1.1480x; 1.1480x over previous
//
#include <hip/hip_runtime.h>
#include <hip/hip_bf16.h>
#include <stdint.h>

// GPTQOFTLinear: y = (x @ R_blockdiag) @ W^T + b
// W' = W with each 64-col block right-multiplied by Q_r^T; y = x @ W'^T + b.
// r10: prep kernel = [cayley (blocks 0-63) || cast_x (blocks 64+)] -> fold -> GEMM.
// GEMM reverted to r8 config (16x16x32 frags, 2-tile unroll, 250us proven; r9's 32x32
// experiment: 32 same-chunk lanes -> structural 4-way LDS conflict, reverted).

typedef __bf16 bf16;
typedef __attribute__((ext_vector_type(4))) __bf16 bf16x4;
typedef __attribute__((ext_vector_type(8))) __bf16 bf16x8;
typedef __attribute__((ext_vector_type(4))) float f32x4;

__device__ __forceinline__ bf16 f2bf(float f) {
  unsigned u = __builtin_bit_cast(unsigned, f);
  u += 0x7fffu + ((u >> 16) & 1u);          // RNE
  unsigned short h = (unsigned short)(u >> 16);
  return __builtin_bit_cast(bf16, h);
}

// ---------------- Kernel 1: prep = cayley (blocks 0-63) || cast_x (blocks 64+) --------
// Cayley: S = 0.5(D-D^T); T = order-6 Neumann for (I+S)^{-1}; Q = (I-S)T.
// Output Q row-major: Qxt[r][i][j] = Q[i][j].  Cast: xb = bf16(x), 8 elems/thread.
__global__ __launch_bounds__(256) void prep_kernel(const float* __restrict__ oft_r,
                                                   float* __restrict__ Qxt,
                                                   const float* __restrict__ x,
                                                   bf16* __restrict__ xb, long n) {
  __shared__ float St[64][68];
  __shared__ float Ta[64][65];
  __shared__ float Tb[64][65];
  const int tid = threadIdx.x;

  if (blockIdx.x >= 64) {
    // ---- cast path ----
    long i0 = ((long)(blockIdx.x - 64) * 256 + tid) * 8;
    long stride = (long)(gridDim.x - 64) * 256 * 8;
    for (long i = i0; i < n; i += stride) {
      f32x4 a = *reinterpret_cast<const f32x4*>(x + i);
      f32x4 b = *reinterpret_cast<const f32x4*>(x + i + 4);
      bf16x8 o;
      o[0] = f2bf(a[0]); o[1] = f2bf(a[1]); o[2] = f2bf(a[2]); o[3] = f2bf(a[3]);
      o[4] = f2bf(b[0]); o[5] = f2bf(b[1]); o[6] = f2bf(b[2]); o[7] = f2bf(b[3]);
      *reinterpret_cast<bf16x8*>(xb + i) = o;
    }
    return;
  }

  // ---- cayley path ----
  const int r = blockIdx.x;
  const float* D = oft_r + (size_t)r * 4096;

  for (int idx = tid; idx < 4096; idx += 256) {
    int i = idx >> 6, j = idx & 63;
    float s = 0.5f * (D[i * 64 + j] - D[j * 64 + i]);
    St[j][i] = s;
    Ta[i][j] = (i == j ? 1.0f : 0.0f) - s;   // T0 = I - S
  }
  __syncthreads();

  const int j = tid & 63;
  const int w = tid >> 6;
  float (*Tin)[65] = Ta;
  float (*Tout)[65] = Tb;

  for (int it = 0; it < 5; ++it) {           // final T = order-6 series
    float out[16];
#pragma unroll
    for (int m = 0; m < 16; ++m) out[m] = ((w * 16 + m) == j ? 1.0f : 0.0f);
    for (int c = 0; c < 64; ++c) {
      float tc = Tin[c][j];
      f32x4 s0 = *reinterpret_cast<const f32x4*>(&St[c][w * 16]);
      f32x4 s1 = *reinterpret_cast<const f32x4*>(&St[c][w * 16 + 4]);
      f32x4 s2 = *reinterpret_cast<const f32x4*>(&St[c][w * 16 + 8]);
      f32x4 s3 = *reinterpret_cast<const f32x4*>(&St[c][w * 16 + 12]);
#pragma unroll
      for (int q = 0; q < 4; ++q) {
        out[q]      -= s0[q] * tc;
        out[4 + q]  -= s1[q] * tc;
        out[8 + q]  -= s2[q] * tc;
        out[12 + q] -= s3[q] * tc;
      }
    }
#pragma unroll
    for (int m = 0; m < 16; ++m) Tout[w * 16 + m][j] = out[m];
    __syncthreads();
    float (*tmp)[65] = Tin; Tin = Tout; Tout = tmp;
  }
  {
    float out[16];
#pragma unroll
    for (int m = 0; m < 16; ++m) out[m] = Tin[w * 16 + m][j];
    for (int c = 0; c < 64; ++c) {
      float tc = Tin[c][j];
      f32x4 s0 = *reinterpret_cast<const f32x4*>(&St[c][w * 16]);
      f32x4 s1 = *reinterpret_cast<const f32x4*>(&St[c][w * 16 + 4]);
      f32x4 s2 = *reinterpret_cast<const f32x4*>(&St[c][w * 16 + 8]);
      f32x4 s3 = *reinterpret_cast<const f32x4*>(&St[c][w * 16 + 12]);
#pragma unroll
      for (int q = 0; q < 4; ++q) {
        out[q]      -= s0[q] * tc;
        out[4 + q]  -= s1[q] * tc;
        out[8 + q]  -= s2[q] * tc;
        out[12 + q] -= s3[q] * tc;
      }
    }
#pragma unroll
    for (int m = 0; m < 16; ++m) Qxt[(size_t)r * 4096 + (w * 16 + m) * 64 + j] = out[m];
  }
}

// ---------------- Kernel 2: fold rotation into W via MFMA ----------------
// Wp[o, r*64+k] = sum_c W[o, r*64+c] * Q[k][c]   (Qxt = Q row-major, consumed B^T-style)
__global__ __launch_bounds__(256) void fold_w_kernel(const float* __restrict__ W,
                                                     const float* __restrict__ Qxt,
                                                     bf16* __restrict__ Wp) {
  __shared__ bf16 Wb[128 * 64];
  __shared__ bf16 Xt[64 * 64];
  const int tid = threadIdx.x;
  const int lane = tid & 63;
  const int wave = tid >> 6;
  const int o0 = blockIdx.x * 128;
  const int r = blockIdx.y;
  const int fr = lane & 15;
  const int kg = lane >> 4;

#pragma unroll
  for (int i = 0; i < 8; ++i) {
    int c = i * 256 + tid;
    int row = c >> 4, c4 = c & 15;
    f32x4 v = *reinterpret_cast<const f32x4*>(W + (size_t)(o0 + row) * 4096 + r * 64 + c4 * 4);
    bf16x4 o; o[0] = f2bf(v[0]); o[1] = f2bf(v[1]); o[2] = f2bf(v[2]); o[3] = f2bf(v[3]);
    *reinterpret_cast<bf16x4*>(&Wb[row * 64 + c4 * 4]) = o;
  }
#pragma unroll
  for (int i = 0; i < 4; ++i) {
    int c = i * 256 + tid;
    int row = c >> 4, c4 = c & 15;
    f32x4 v = *reinterpret_cast<const f32x4*>(Qxt + (size_t)r * 4096 + row * 64 + c4 * 4);
    bf16x4 o; o[0] = f2bf(v[0]); o[1] = f2bf(v[1]); o[2] = f2bf(v[2]); o[3] = f2bf(v[3]);
    *reinterpret_cast<bf16x4*>(&Xt[row * 64 + c4 * 4]) = o;
  }
  __syncthreads();

  const int wm = wave * 32;
  f32x4 acc[2][4];
#pragma unroll
  for (int mi = 0; mi < 2; ++mi)
#pragma unroll
    for (int ni = 0; ni < 4; ++ni) acc[mi][ni] = (f32x4){0.f, 0.f, 0.f, 0.f};

#pragma unroll
  for (int kk = 0; kk < 64; kk += 32) {
    bf16x8 af[2], bx[4];
#pragma unroll
    for (int mi = 0; mi < 2; ++mi)
      af[mi] = *reinterpret_cast<const bf16x8*>(&Wb[(wm + mi * 16 + fr) * 64 + kk + kg * 8]);
#pragma unroll
    for (int ni = 0; ni < 4; ++ni)
      bx[ni] = *reinterpret_cast<const bf16x8*>(&Xt[(ni * 16 + fr) * 64 + kk + kg * 8]);
#pragma unroll
    for (int mi = 0; mi < 2; ++mi)
#pragma unroll
      for (int ni = 0; ni < 4; ++ni)
        acc[mi][ni] = __builtin_amdgcn_mfma_f32_16x16x32_bf16(af[mi], bx[ni], acc[mi][ni], 0, 0, 0);
  }

#pragma unroll
  for (int mi = 0; mi < 2; ++mi)
#pragma unroll
    for (int ni = 0; ni < 4; ++ni)
#pragma unroll
      for (int q = 0; q < 4; ++q) {
        int row = o0 + wm + mi * 16 + kg * 4 + q;
        int col = ni * 16 + fr;
        Wp[(size_t)row * 4096 + r * 64 + col] = f2bf(acc[mi][ni][q]);
      }
}

// ---------------- Kernel 3: 256x256 8-phase GEMM, y = xb @ Wp^T + b (r8 config) -------
// A [M,K] bf16 row-major, B [N,K] bf16 row-major (B^T layout), C [M,N] f32.
// 512 thr = 8 waves (2M x 4N), BK=64 in two K-halves, double-buffered 128 KiB LDS.
// LDS layout: [buf(2)][op(A,B)][ks(2)][row(256)][chunk(4)*8], swizzle key (row>>1)&3
// (conflict-free: 16-lane groups per chunk -> 2-way = free).
// Ledger: STAGE pair p of next tile at phase p; vmcnt(4) at P1 publishes this tile's ks1,
// vmcnt(4) at P3 publishes next tile's ks0; vmcnt(0) only on last tile.
// 2-tile unroll: all LDS offsets literal. Phase: {ds_reads; STAGE; [vmcnt]; barrier;
// setprio(1); 16 MFMA; setprio(0); barrier}.

#define GLDS16(g, l) __builtin_amdgcn_global_load_lds( \
    (const __attribute__((address_space(1))) unsigned int*)(g), \
    (__attribute__((address_space(3))) unsigned int*)(l), 16, 0, 0)

#define VMCNT4 asm volatile("s_waitcnt vmcnt(4)" ::: "memory")
#define VMCNT0 asm volatile("s_waitcnt vmcnt(0)" ::: "memory")
#define BARRIER() do { asm volatile("" ::: "memory"); \
  __builtin_amdgcn_s_barrier(); asm volatile("" ::: "memory"); } while (0)

#define MFMA16(AF, BF, RB) \
  _Pragma("unroll") \
  for (int m_ = 0; m_ < 4; ++m_) \
    _Pragma("unroll") \
    for (int n_ = 0; n_ < 4; ++n_) \
      acc[RB + m_][n_] = __builtin_amdgcn_mfma_f32_16x16x32_bf16(AF[m_], BF[n_], acc[RB + m_][n_], 0, 0, 0);

// One K-tile (4 phases). BUF = literal LDS buffer of this tile; TN = tile staged (t+1);
// PRE = whether TN exists. Stages go to buffer BUF^1.
#define DO_TILE(BUF, TN, PRE) do { \
    /* P0: ks0 mi0-3 */ \
    _Pragma("unroll") for (int n_ = 0; n_ < 4; ++n_) Ob[n_] = LDB(BUF, 0, n_); \
    _Pragma("unroll") for (int m_ = 0; m_ < 4; ++m_) Oa[m_] = LDA(BUF, 0, m_); \
    if (PRE) STAGE(TN, BUF ^ 1, 0); \
    BARRIER(); \
    __builtin_amdgcn_s_setprio(1); MFMA16(Oa, Ob, 0) __builtin_amdgcn_s_setprio(0); \
    BARRIER(); \
    /* P1: ks0 mi4-7 */ \
    _Pragma("unroll") for (int m_ = 0; m_ < 4; ++m_) Ea[m_] = LDA(BUF, 0, 4 + m_); \
    if (PRE) STAGE(TN, BUF ^ 1, 1); \
    if (PRE) { VMCNT4; } else { VMCNT0; } \
    BARRIER(); \
    __builtin_amdgcn_s_setprio(1); MFMA16(Ea, Ob, 4) __builtin_amdgcn_s_setprio(0); \
    BARRIER(); \
    /* P2: ks1 mi0-3 */ \
    _Pragma("unroll") for (int n_ = 0; n_ < 4; ++n_) Eb[n_] = LDB(BUF, 1, n_); \
    _Pragma("unroll") for (int m_ = 0; m_ < 4; ++m_) Oa[m_] = LDA(BUF, 1, m_); \
    if (PRE) STAGE(TN, BUF ^ 1, 2); \
    BARRIER(); \
    __builtin_amdgcn_s_setprio(1); MFMA16(Oa, Eb, 0) __builtin_amdgcn_s_setprio(0); \
    BARRIER(); \
    /* P3: ks1 mi4-7 */ \
    _Pragma("unroll") for (int m_ = 0; m_ < 4; ++m_) Ea[m_] = LDA(BUF, 1, 4 + m_); \
    if (PRE) STAGE(TN, BUF ^ 1, 3); \
    if (PRE) { VMCNT4; } else { VMCNT0; } \
    BARRIER(); \
    __builtin_amdgcn_s_setprio(1); MFMA16(Ea, Eb, 4) __builtin_amdgcn_s_setprio(0); \
    BARRIER(); \
  } while (0)

__global__ __launch_bounds__(512, 2) void gemm_kernel(const bf16* __restrict__ A,
                                                      const bf16* __restrict__ B,
                                                      const float* __restrict__ bias,
                                                      float* __restrict__ C,
                                                      int M, int N, int K) {
  __shared__ bf16 lds[65536];   // 128 KiB
  const int tid = threadIdx.x;
  const int lane = tid & 63;
  const int wave = tid >> 6;
  const int wr = wave >> 2;          // 0..1  (M)
  const int wc = wave & 3;           // 0..3  (N)
  const int fr = lane & 15;
  const int kg = lane >> 4;
  const int m0 = blockIdx.y * 256;
  const int n0 = blockIdx.x * 256;
  const int NT = K >> 6;             // even (4096/64 = 64)

  f32x4 acc[8][4];
#pragma unroll
  for (int m = 0; m < 8; ++m)
#pragma unroll
    for (int n = 0; n < 4; ++n) acc[m][n] = (f32x4){0.f, 0.f, 0.f, 0.f};

  // stage pair p (0:A-ks0 1:B-ks0 2:A-ks1 3:B-ks1) of K-tile t into LDS buffer db
  auto STAGE = [&](int t, int db, int p) {
    const int op = p & 1, ks = p >> 1;
    const bf16* src = op ? B : A;
    const int base_row = op ? n0 : m0;
    const int ldsb = db * 32768 + op * 16384 + ks * 8192;
#pragma unroll
    for (int i = 0; i < 2; ++i) {
      int c = i * 512 + tid;           // 1024 chunks of 16B per half-tile
      int row = c >> 2, cc = c & 3;
      const bf16* g = src + (size_t)(base_row + row) * K + t * 64 + ks * 32
                      + ((cc ^ ((row >> 1) & 3)) << 3);      // inverse-swizzled source
      GLDS16(g, &lds[ldsb + ((i * 512 + wave * 64) << 3)]); // linear dest (+lane*16B by HW)
    }
  };
  auto LDA = [&](int buf, int ks, int mi) -> bf16x8 {
    int row = wr * 128 + mi * 16 + fr;
    return *reinterpret_cast<const bf16x8*>(
        &lds[buf * 32768 + ks * 8192 + row * 32 + ((kg ^ ((row >> 1) & 3)) << 3)]);
  };
  auto LDB = [&](int buf, int ks, int ni) -> bf16x8 {
    int row = wc * 64 + ni * 16 + fr;
    return *reinterpret_cast<const bf16x8*>(
        &lds[buf * 32768 + 16384 + ks * 8192 + row * 32 + ((kg ^ ((row >> 1) & 3)) << 3)]);
  };

  // prologue: stage tile 0 into buf0; publish its ks0 halves (ks1 pair stays in flight)
#pragma unroll
  for (int p = 0; p < 4; ++p) STAGE(0, 0, p);
  VMCNT4;
  BARRIER();

  bf16x8 Oa[4], Ob[4], Ea[4], Eb[4];
  for (int t = 0; t < NT; t += 2) {
    DO_TILE(0, t + 1, true);             // t+1 <= NT-1 always
    DO_TILE(1, t + 2, (t + 2) < NT);
  }

  // epilogue: D row = kg*4+q (+16*m blocks), col = fr (+16*n)
#pragma unroll
  for (int n = 0; n < 4; ++n) {
    int col = n0 + wc * 64 + n * 16 + fr;
    float bv = bias[col];
#pragma unroll
    for (int m = 0; m < 8; ++m) {
      int row0 = m0 + wr * 128 + m * 16 + kg * 4;
#pragma unroll
      for (int q = 0; q < 4; ++q)
        C[(size_t)(row0 + q) * N + col] = acc[m][n][q] + bv;
    }
  }
}

extern "C" void kernel_launch(void* const* d_in, const int* in_sizes, int n_in,
                              void* d_out, int out_size, void* d_ws, size_t ws_size,
                              hipStream_t stream) {
  const float* x     = (const float*)d_in[0];   // [2,4096,4096]
  const float* oft_r = (const float*)d_in[1];   // [64,64,64]
  const float* W     = (const float*)d_in[2];   // [4096,4096]
  const float* b     = (const float*)d_in[3];   // [4096]
  float* y = (float*)d_out;                     // [8192,4096] f32

  char* ws = (char*)d_ws;
  float* Qxt = (float*)ws;                                 // 1 MiB: Q row-major per block
  bf16*  Wp  = (bf16*)(ws + (1u << 20));                   // 32 MiB: folded W, bf16
  bf16*  xb  = (bf16*)(ws + (1u << 20) + (32u << 20));     // 64 MiB: x, bf16

  prep_kernel<<<2112, 256, 0, stream>>>(oft_r, Qxt, x, xb, 33554432L);
  dim3 fg(32, 64);
  fold_w_kernel<<<fg, 256, 0, stream>>>(W, Qxt, Wp);
  dim3 gg(4096 / 256, 8192 / 256);   // (16, 32)
  gemm_kernel<<<gg, 512, 0, stream>>>(xb, Wp, b, y, 8192, 4096, 4096);
}